// Round 5
// baseline (424.064 us; speedup 1.0000x reference)
//
#include <hip/hip_runtime.h>
#include <cmath>

#define BATCH 64
#define NTOK  4096
#define DIM   256
#define NCLS  20
#define TILE  32
#define XPAD  65   // float4 stride per Xs row; this access family measured 0 conflicts

// async global->LDS, 16B/lane; dest must be wave-uniform base + lane*16 (it is).
#define GLOAD_LDS16(gp, lp) \
  __builtin_amdgcn_global_load_lds((const __attribute__((address_space(1))) void*)(gp), \
                                   (__attribute__((address_space(3))) void*)(lp), 16, 0, 0)

// v + rotated(v) within each 16-lane DPP row — pure VALU, off the LDS pipe.
template <int CTRL>
__device__ __forceinline__ float dpp_add(float v) {
  int x = __builtin_amdgcn_update_dpp(0, __float_as_int(v), CTRL, 0xF, 0xF, false);
  return v + __int_as_float(x);
}

// Full sum over a 32-lane half (lane = 32r + s): 4 DPP rotations give the
// row-of-16 allsum in every lane; one xor16 swizzle merges the two rows.
__device__ __forceinline__ float allreduce32(float v) {
  v = dpp_add<0x128>(v);   // row_ror:8
  v = dpp_add<0x124>(v);   // row_ror:4
  v = dpp_add<0x122>(v);   // row_ror:2
  v = dpp_add<0x121>(v);   // row_ror:1
  return v + __shfl_xor(v, 16, 64);
}

__device__ __forceinline__ float wave_sum64(float v) {
  #pragma unroll
  for (int m = 32; m >= 1; m >>= 1) v += __shfl_xor(v, m, 64);
  return v;
}

// One block per (batch, n-chunk); 4 waves; wave w owns classes [5w,5w+5).
// Lane = (r = lane>>5: row parity, s = lane&31: 8-dim slice).
// Codebook slice in VGPRs (pre-scaled by log2e); X staged once in LDS and read
// once; scores DPP-allreduced; o accumulated as per-lane slice partials.
__global__ __launch_bounds__(256, 4) void patch_attn_chunk(
    const float* __restrict__ patch, const float* __restrict__ codebook,
    float* __restrict__ o_ws, float* __restrict__ l_ws, int nch) {
  __shared__ float4 Xs[TILE * XPAD];   // 33,280 B -> 4 blocks/CU

  const int tid  = threadIdx.x;
  const int w    = tid >> 6;
  const int lane = tid & 63;
  const int r    = lane >> 5;          // which row parity this lane covers
  const int s    = lane & 31;          // dims 8s..8s+7
  const int b    = blockIdx.x / nch;
  const int ch   = blockIdx.x - b * nch;
  const int rows = NTOK / nch;         // 256 at nch=16
  const int ntiles = rows / TILE;      // 8
  const float4* Xg  = (const float4*)patch + ((size_t)b * NTOK + (size_t)ch * rows) * (DIM / 4);
  const float4* cb4 = (const float4*)codebook;
  const int c0 = __builtin_amdgcn_readfirstlane(w * 5);

  // ---- codebook slice -> registers, scaled by log2(e) so p = exp2f(score) ----
  float4 cb[5][2];
  #pragma unroll
  for (int j = 0; j < 5; ++j) {
    #pragma unroll
    for (int i = 0; i < 2; ++i) {
      float4 v = cb4[(c0 + j) * (DIM / 4) + 2 * s + i];
      const float k = 1.4426950408889634f;
      cb[j][i] = make_float4(v.x * k, v.y * k, v.z * k, v.w * k);
    }
  }

  float4 o[5][2];              // slice-partial accumulator (this lane's 8 dims)
  float l_run[5];
  #pragma unroll
  for (int j = 0; j < 5; ++j) {
    o[j][0] = make_float4(0.f, 0.f, 0.f, 0.f);
    o[j][1] = make_float4(0.f, 0.f, 0.f, 0.f);
    l_run[j] = 0.f;
  }

  for (int t = 0; t < ntiles; ++t) {
    // ---- stage 32-row tile via global->LDS DMA (one row per wave-instr) ----
    const float4* srcT = Xg + (size_t)t * TILE * (DIM / 4);
    #pragma unroll
    for (int i = 0; i < 8; ++i) {
      const int n = i * 4 + w;
      GLOAD_LDS16(srcT + n * (DIM / 4) + lane, &Xs[n * XPAD + lane]);
    }
    __syncthreads();   // drains vmcnt -> tile valid

    // ---- fused A+B: group g covers rows {2g, 2g+1}; lane does row 2g+r ----
    #pragma unroll 4
    for (int g = 0; g < 16; ++g) {
      const int R = 2 * g + r;
      float4 x0 = Xs[R * XPAD + 2 * s];
      float4 x1 = Xs[R * XPAD + 2 * s + 1];
      #pragma unroll
      for (int j = 0; j < 5; ++j) {
        float sj = x0.x * cb[j][0].x;
        sj = fmaf(x0.y, cb[j][0].y, sj);
        sj = fmaf(x0.z, cb[j][0].z, sj);
        sj = fmaf(x0.w, cb[j][0].w, sj);
        sj = fmaf(x1.x, cb[j][1].x, sj);
        sj = fmaf(x1.y, cb[j][1].y, sj);
        sj = fmaf(x1.z, cb[j][1].z, sj);
        sj = fmaf(x1.w, cb[j][1].w, sj);
        sj = allreduce32(sj);            // full 256-dim dot (log2 units)
        float p = exp2f(sj);             // = exp(score); bounded, no-max safe
        l_run[j] += p;
        o[j][0].x = fmaf(p, x0.x, o[j][0].x);
        o[j][0].y = fmaf(p, x0.y, o[j][0].y);
        o[j][0].z = fmaf(p, x0.z, o[j][0].z);
        o[j][0].w = fmaf(p, x0.w, o[j][0].w);
        o[j][1].x = fmaf(p, x1.x, o[j][1].x);
        o[j][1].y = fmaf(p, x1.y, o[j][1].y);
        o[j][1].z = fmaf(p, x1.z, o[j][1].z);
        o[j][1].w = fmaf(p, x1.w, o[j][1].w);
      }
    }
    __syncthreads();   // protect Xs before next tile's staging
  }

  // ---- merge the two row-parity halves (xor32) + reduce l ----
  #pragma unroll
  for (int j = 0; j < 5; ++j) {
    #pragma unroll
    for (int i = 0; i < 2; ++i) {
      o[j][i].x += __shfl_xor(o[j][i].x, 32, 64);
      o[j][i].y += __shfl_xor(o[j][i].y, 32, 64);
      o[j][i].z += __shfl_xor(o[j][i].z, 32, 64);
      o[j][i].w += __shfl_xor(o[j][i].w, 32, 64);
    }
    l_run[j] = wave_sum64(l_run[j]) * (1.0f / 32.0f);  // 32 s-lanes duplicate
  }

  // ---- write per-chunk partials ----
  const size_t base = (size_t)(b * nch + ch) * NCLS + c0;
  float4* og = (float4*)o_ws;
  if (r == 0) {
    #pragma unroll
    for (int j = 0; j < 5; ++j) {
      og[(base + j) * (DIM / 4) + 2 * s    ] = o[j][0];
      og[(base + j) * (DIM / 4) + 2 * s + 1] = o[j][1];
    }
  }
  if (lane == 0) {
    #pragma unroll
    for (int j = 0; j < 5; ++j) l_ws[base + j] = l_run[j];
  }
}

// Merge nch chunk-partials per (b,c): out = sum(o) / sum(l).
__global__ __launch_bounds__(256) void patch_attn_combine(
    const float* __restrict__ o_ws, const float* __restrict__ l_ws,
    float* __restrict__ out, int nch) {
  const int bc = blockIdx.x;            // b*NCLS + c
  const int b = bc / NCLS;
  const int c = bc - b * NCLS;
  const int d = threadIdx.x;

  float lg = 0.f, acc = 0.f;
  for (int ch = 0; ch < nch; ++ch) {
    size_t idx = ((size_t)b * nch + ch) * NCLS + c;
    lg  += l_ws[idx];
    acc += o_ws[idx * DIM + d];
  }
  out[(size_t)bc * DIM + d] = acc / lg;
}

extern "C" void kernel_launch(void* const* d_in, const int* in_sizes, int n_in,
                              void* d_out, int out_size, void* d_ws, size_t ws_size,
                              hipStream_t stream) {
  const float* patch = (const float*)d_in[0];
  const float* cbk   = (const float*)d_in[1];
  float* out = (float*)d_out;

  // nch=16 -> 1024 blocks -> 4 resident/CU. Fallback halves if ws small.
  int nch = 16;
  while (nch > 1 && (size_t)BATCH * nch * NCLS * (DIM + 1) * sizeof(float) > ws_size) nch >>= 1;

  float* o_ws = (float*)d_ws;                                  // [B][nch][NCLS][DIM]
  float* l_ws = o_ws + (size_t)BATCH * nch * NCLS * DIM;       // [B][nch][NCLS]

  patch_attn_chunk<<<dim3(BATCH * nch), dim3(256), 0, stream>>>(patch, cbk, o_ws, l_ws, nch);
  patch_attn_combine<<<dim3(BATCH * NCLS), dim3(256), 0, stream>>>(o_ws, l_ws, out, nch);
}